// Round 1
// baseline (829.234 us; speedup 1.0000x reference)
//
#include <hip/hip_runtime.h>
#include <math.h>

#define NE 200000
#define NR 16
#define DD 128
#define BB 4096
#define SS 64
#define LL 2
#define HH 4

// block-wide (128 threads = 2 waves) sum reduction
__device__ __forceinline__ float block_sum128(float v, float* scr, int t) {
    #pragma unroll
    for (int off = 32; off > 0; off >>= 1) v += __shfl_down(v, off, 64);
    __syncthreads();                 // protect scr from previous use
    if ((t & 63) == 0) scr[t >> 6] = v;
    __syncthreads();
    return scr[0] + scr[1];
}

extern "C" __global__ __launch_bounds__(128)
void rgcn_attn_fused(const int* __restrict__ drug_idx,
                     const int* __restrict__ adj_ent,
                     const int* __restrict__ adj_rel,
                     const float* __restrict__ ew,
                     const float* __restrict__ emb,
                     const float* __restrict__ W_rgcn,
                     const float* __restrict__ res_w, const float* __restrict__ res_b,
                     const float* __restrict__ proj_w, const float* __restrict__ proj_b,
                     const float* __restrict__ ln_g, const float* __restrict__ ln_b,
                     const float* __restrict__ in_w, const float* __restrict__ in_b,
                     const float* __restrict__ out_w, const float* __restrict__ out_b,
                     const float* __restrict__ fg, const float* __restrict__ fb,
                     float* __restrict__ out)
{
    const int b = blockIdx.x;
    const int t = threadIdx.x;    // 0..127, also the feature dim this thread owns

    __shared__ float pre[NR * DD];     // 8 KB per-relation accumulators
    __shared__ float node[DD];
    __shared__ float hbuf[DD];
    __shared__ float xs[LL][DD];
    __shared__ float qb[LL][DD], kb[LL][DD], vb[LL][DD], ob[LL][DD];
    __shared__ float scr[2];

    // ---- gather node embedding + per-relation weighted neighbor sums ----
    node[t] = emb[(long)drug_idx[b] * DD + t];
    #pragma unroll
    for (int r = 0; r < NR; ++r) pre[r * DD + t] = 0.f;
    // each thread owns column t of pre -> no races in the s-loop
    for (int s = 0; s < SS; ++s) {
        int e = adj_ent[b * SS + s];
        int r = adj_rel[b * SS + s];
        float w = ew[b * SS + s];
        pre[r * DD + t] = fmaf(emb[(long)e * DD + t], w, pre[r * DD + t]);
    }
    __syncthreads();

    // ---- RGCN layers ----
    for (int l = 0; l < LL; ++l) {
        // msgs[t] = sum_{rd} pre[rd] * W[l, rd, t]
        const float* Wl = W_rgcn + (size_t)l * NR * DD * DD;
        float msg = 0.f;
        for (int rd = 0; rd < NR * DD; ++rd)
            msg = fmaf(pre[rd], Wl[(size_t)rd * DD + t], msg);

        // res[t] = res_b + sum_d node[d] * res_w[l, t, d]
        float nt = node[t];
        float rr = res_b[l * DD + t];
        const float* Rw = res_w + ((size_t)l * DD + t) * DD;
        for (int d = 0; d < DD; ++d)
            rr = fmaf(node[d], Rw[d], rr);

        float hv = nt + msg + rr;
        hv = hv > 0.f ? hv : 0.f;
        hbuf[t] = hv;
        __syncthreads();

        // proj[t] = proj_b + sum_d h[d] * proj_w[l, t, d] + node[t]
        float pp = proj_b[l * DD + t];
        const float* Pw = proj_w + ((size_t)l * DD + t) * DD;
        for (int d = 0; d < DD; ++d)
            pp = fmaf(hbuf[d], Pw[d], pp);
        pp += nt;

        // LayerNorm over the 128 features
        float mean = block_sum128(pp, scr, t) * (1.f / DD);
        float df = pp - mean;
        float var = block_sum128(df * df, scr, t) * (1.f / DD);
        float val = df * rsqrtf(var + 1e-5f) * ln_g[l * DD + t] + ln_b[l * DD + t];
        __syncthreads();           // everyone done reading node/scr
        node[t] = val;
        xs[l][t] = val;
        __syncthreads();
    }

    // ---- qkv projections ----
    {
        const float* Qw = in_w + (size_t)t * DD;
        const float* Kw = in_w + ((size_t)DD + t) * DD;
        const float* Vw = in_w + ((size_t)2 * DD + t) * DD;
        float qb0 = in_b[t], kb0 = in_b[DD + t], vb0 = in_b[2 * DD + t];
        for (int l = 0; l < LL; ++l) {
            float qa = qb0, ka = kb0, va = vb0;
            for (int d = 0; d < DD; ++d) {
                float xv = xs[l][d];
                qa = fmaf(xv, Qw[d], qa);
                ka = fmaf(xv, Kw[d], ka);
                va = fmaf(xv, Vw[d], va);
            }
            qb[l][t] = qa; kb[l][t] = ka; vb[l][t] = va;
        }
    }
    __syncthreads();

    // ---- attention over L=2 (heads of 32 dims; 32-lane groups stay inside a wave) ----
    const float scale = rsqrtf(32.f);
    float sc[LL][LL];
    #pragma unroll
    for (int l = 0; l < LL; ++l)
        #pragma unroll
        for (int m = 0; m < LL; ++m) {
            float prod = qb[l][t] * kb[m][t];
            #pragma unroll
            for (int off = 16; off > 0; off >>= 1)
                prod += __shfl_xor(prod, off, 64);
            sc[l][m] = prod * scale;
        }
    #pragma unroll
    for (int l = 0; l < LL; ++l) {
        float a = sc[l][0], c = sc[l][1];
        float mx = fmaxf(a, c);
        float e0 = expf(a - mx), e1 = expf(c - mx);
        float inv = 1.f / (e0 + e1);
        ob[l][t] = (e0 * vb[0][t] + e1 * vb[1][t]) * inv;
    }
    __syncthreads();

    // ---- output projection, mean over L, final LayerNorm ----
    const float* Ow = out_w + (size_t)t * DD;
    float o0 = out_b[t], o1 = out_b[t];
    for (int d = 0; d < DD; ++d) {
        float w = Ow[d];
        o0 = fmaf(ob[0][d], w, o0);
        o1 = fmaf(ob[1][d], w, o1);
    }
    float avg = 0.5f * (o0 + o1);
    float mean = block_sum128(avg, scr, t) * (1.f / DD);
    float df = avg - mean;
    float var = block_sum128(df * df, scr, t) * (1.f / DD);
    out[(size_t)b * DD + t] = df * rsqrtf(var + 1e-5f) * fg[t] + fb[t];
}

extern "C" void kernel_launch(void* const* d_in, const int* in_sizes, int n_in,
                              void* d_out, int out_size, void* d_ws, size_t ws_size,
                              hipStream_t stream) {
    const int*   drug_idx = (const int*)d_in[0];
    const int*   adj_ent  = (const int*)d_in[1];
    const int*   adj_rel  = (const int*)d_in[2];
    const float* ew       = (const float*)d_in[3];
    const float* emb      = (const float*)d_in[4];
    const float* W_rgcn   = (const float*)d_in[5];
    const float* res_w    = (const float*)d_in[6];
    const float* res_b    = (const float*)d_in[7];
    const float* proj_w   = (const float*)d_in[8];
    const float* proj_b   = (const float*)d_in[9];
    const float* ln_g     = (const float*)d_in[10];
    const float* ln_b     = (const float*)d_in[11];
    const float* in_w     = (const float*)d_in[12];
    const float* in_b     = (const float*)d_in[13];
    const float* out_w    = (const float*)d_in[14];
    const float* out_b    = (const float*)d_in[15];
    const float* fg       = (const float*)d_in[16];
    const float* fb       = (const float*)d_in[17];
    float* out = (float*)d_out;

    hipLaunchKernelGGL(rgcn_attn_fused, dim3(BB), dim3(128), 0, stream,
                       drug_idx, adj_ent, adj_rel, ew, emb, W_rgcn,
                       res_w, res_b, proj_w, proj_b, ln_g, ln_b,
                       in_w, in_b, out_w, out_b, fg, fb, out);
}

// Round 2
// 272.885 us; speedup vs baseline: 3.0388x; 3.0388x over previous
//
#include <hip/hip_runtime.h>
#include <math.h>

#define NRREL 16
#define DDIM 128
#define BBATCH 4096
#define SNBR 64

typedef __attribute__((ext_vector_type(8))) short short8;
typedef __attribute__((ext_vector_type(4))) float floatx4;

__device__ __forceinline__ unsigned short f2bf(float f) {
    unsigned u = __builtin_bit_cast(unsigned, f);
    u += 0x7fffu + ((u >> 16) & 1u);
    return (unsigned short)(u >> 16);
}

// ---------------- gather: node emb + per-relation weighted neighbor sums (bf16 out) ----
extern "C" __global__ __launch_bounds__(128)
void k_gather(const int* __restrict__ drug, const int* __restrict__ adj_e,
              const int* __restrict__ adj_r, const float* __restrict__ ew,
              const float* __restrict__ emb,
              unsigned short* __restrict__ pre_bf,
              float* __restrict__ node_f, unsigned short* __restrict__ node_bf)
{
    const int b = blockIdx.x, t = threadIdx.x;
    __shared__ float pre[NRREL * DDIM];
    #pragma unroll
    for (int r = 0; r < NRREL; ++r) pre[r * DDIM + t] = 0.f;
    float nf = emb[(size_t)drug[b] * DDIM + t];
    node_f[(size_t)b * DDIM + t] = nf;
    node_bf[(size_t)b * DDIM + t] = f2bf(nf);
    const int base = b * SNBR;
    #pragma unroll 4
    for (int s = 0; s < SNBR; ++s) {
        int e = adj_e[base + s];
        int r = adj_r[base + s];
        float w = ew[base + s];
        pre[r * DDIM + t] = fmaf(emb[(size_t)e * DDIM + t], w, pre[r * DDIM + t]);
    }
    #pragma unroll
    for (int r = 0; r < NRREL; ++r)
        pre_bf[(size_t)b * 2048 + r * DDIM + t] = f2bf(pre[r * DDIM + t]);
}

// ---------------- weight convert (+ W_rgcn transpose to [N=256][K=2048]) ---------------
extern "C" __global__ __launch_bounds__(256)
void k_wconv(const float* __restrict__ W_rgcn, const float* __restrict__ res_w,
             const float* __restrict__ proj_w, const float* __restrict__ in_w,
             const float* __restrict__ out_w,
             unsigned short* __restrict__ Wcat, unsigned short* __restrict__ resw,
             unsigned short* __restrict__ projw, unsigned short* __restrict__ inw,
             unsigned short* __restrict__ outw)
{
    int i = blockIdx.x * 256 + threadIdx.x;
    if (i < 524288) {               // Wcat[n][k] = W_rgcn[l][k][e], n = l*128+e
        int n = i >> 11, k = i & 2047;
        int l = n >> 7, e = n & 127;
        Wcat[i] = f2bf(W_rgcn[((size_t)l * 2048 + k) * 128 + e]);
    } else {
        int j = i - 524288;
        if (j < 32768)       resw[j] = f2bf(res_w[j]);
        else if (j < 65536)  projw[j - 32768] = f2bf(proj_w[j - 32768]);
        else if (j < 114688) inw[j - 65536] = f2bf(in_w[j - 65536]);
        else                 outw[j - 114688] = f2bf(out_w[j - 114688]);
    }
}

// ---------------- core 32x32 wave tile: C = A[M,K] x Bt[N,K]^T, bf16 MFMA -------------
__device__ __forceinline__ void gemm32x32(const unsigned short* __restrict__ A,
                                          const unsigned short* __restrict__ Bt,
                                          int K, int r0, int c0, floatx4 acc[2][2])
{
    int lane = threadIdx.x & 63;
    int l15 = lane & 15, q = lane >> 4;
    const unsigned short* a0 = A + (size_t)(r0 + l15) * K + q * 8;
    const unsigned short* a1 = a0 + (size_t)16 * K;
    const unsigned short* b0 = Bt + (size_t)(c0 + l15) * K + q * 8;
    const unsigned short* b1 = b0 + (size_t)16 * K;
    #pragma unroll 2
    for (int k = 0; k < K; k += 32) {
        short8 A0 = *(const short8*)(a0 + k);
        short8 A1 = *(const short8*)(a1 + k);
        short8 B0 = *(const short8*)(b0 + k);
        short8 B1 = *(const short8*)(b1 + k);
        acc[0][0] = __builtin_amdgcn_mfma_f32_16x16x32_bf16(A0, B0, acc[0][0], 0, 0, 0);
        acc[0][1] = __builtin_amdgcn_mfma_f32_16x16x32_bf16(A0, B1, acc[0][1], 0, 0, 0);
        acc[1][0] = __builtin_amdgcn_mfma_f32_16x16x32_bf16(A1, B0, acc[1][0], 0, 0, 0);
        acc[1][1] = __builtin_amdgcn_mfma_f32_16x16x32_bf16(A1, B1, acc[1][1], 0, 0, 0);
    }
}

// ---------------- msgs = pre x Wcat^T : [4096,2048]x[2048,256] ------------------------
extern "C" __global__ __launch_bounds__(256)
void k_msgs(const unsigned short* __restrict__ pre_bf,
            const unsigned short* __restrict__ Wcat, float* __restrict__ msgs)
{
    int wave = threadIdx.x >> 6, wm = wave >> 1, wn = wave & 1;
    int r0 = blockIdx.x * 64 + wm * 32;
    int c0 = blockIdx.y * 64 + wn * 32;
    floatx4 acc[2][2] = {};
    gemm32x32(pre_bf, Wcat, 2048, r0, c0, acc);
    int lane = threadIdx.x & 63, l15 = lane & 15, q = lane >> 4;
    for (int mi = 0; mi < 2; ++mi)
        for (int ni = 0; ni < 2; ++ni) {
            int gc = c0 + ni * 16 + l15;
            #pragma unroll
            for (int r = 0; r < 4; ++r) {
                int gr = r0 + mi * 16 + 4 * q + r;
                msgs[(size_t)gr * 256 + gc] = acc[mi][ni][r];
            }
        }
}

// ---------------- h = relu(node + msgs_l + node x res_w_l^T + res_b) ------------------
extern "C" __global__ __launch_bounds__(256)
void k_res(const unsigned short* __restrict__ node_bf, const unsigned short* __restrict__ resw,
           const float* __restrict__ res_b, const float* __restrict__ node_f,
           const float* __restrict__ msgs, unsigned short* __restrict__ h_bf, int l)
{
    int wave = threadIdx.x >> 6, wm = wave >> 1, wn = wave & 1;
    int r0 = blockIdx.x * 64 + wm * 32;
    int c0 = blockIdx.y * 64 + wn * 32;
    floatx4 acc[2][2] = {};
    gemm32x32(node_bf, resw + (size_t)l * DDIM * DDIM, DDIM, r0, c0, acc);
    int lane = threadIdx.x & 63, l15 = lane & 15, q = lane >> 4;
    for (int mi = 0; mi < 2; ++mi)
        for (int ni = 0; ni < 2; ++ni) {
            int gc = c0 + ni * 16 + l15;
            float rb = res_b[l * DDIM + gc];
            #pragma unroll
            for (int r = 0; r < 4; ++r) {
                int gr = r0 + mi * 16 + 4 * q + r;
                float v = acc[mi][ni][r] + rb + node_f[(size_t)gr * DDIM + gc]
                        + msgs[(size_t)gr * 256 + l * DDIM + gc];
                v = v > 0.f ? v : 0.f;
                h_bf[(size_t)gr * DDIM + gc] = f2bf(v);
            }
        }
}

// ---------------- node = LN(h x proj_w_l^T + proj_b + node); also xs[2b+l] ------------
extern "C" __global__ __launch_bounds__(256)
void k_proj(const unsigned short* __restrict__ h_bf, const unsigned short* __restrict__ projw,
            const float* __restrict__ proj_b, const float* __restrict__ ln_g,
            const float* __restrict__ ln_b, float* __restrict__ node_f,
            unsigned short* __restrict__ node_bf, unsigned short* __restrict__ xs_bf, int l)
{
    int wave = threadIdx.x >> 6;
    int r0 = (blockIdx.x * 4 + wave) * 16;
    int lane = threadIdx.x & 63, l15 = lane & 15, q = lane >> 4;
    const unsigned short* Bt = projw + (size_t)l * DDIM * DDIM;
    floatx4 acc[8] = {};
    const unsigned short* ap = h_bf + (size_t)(r0 + l15) * DDIM + q * 8;
    #pragma unroll
    for (int k = 0; k < DDIM; k += 32) {
        short8 A0 = *(const short8*)(ap + k);
        #pragma unroll
        for (int ni = 0; ni < 8; ++ni) {
            short8 B = *(const short8*)(Bt + (size_t)(ni * 16 + l15) * DDIM + q * 8 + k);
            acc[ni] = __builtin_amdgcn_mfma_f32_16x16x32_bf16(A0, B, acc[ni], 0, 0, 0);
        }
    }
    float vv[4][8];
    float s[4] = {0, 0, 0, 0}, sq[4] = {0, 0, 0, 0};
    #pragma unroll
    for (int ni = 0; ni < 8; ++ni) {
        int gc = ni * 16 + l15;
        float pb = proj_b[l * DDIM + gc];
        #pragma unroll
        for (int r = 0; r < 4; ++r) {
            int gr = r0 + 4 * q + r;
            float v = acc[ni][r] + pb + node_f[(size_t)gr * DDIM + gc];
            vv[r][ni] = v; s[r] += v; sq[r] += v * v;
        }
    }
    #pragma unroll
    for (int r = 0; r < 4; ++r)
        #pragma unroll
        for (int off = 8; off >= 1; off >>= 1) {
            s[r] += __shfl_xor(s[r], off, 64);
            sq[r] += __shfl_xor(sq[r], off, 64);
        }
    #pragma unroll
    for (int ni = 0; ni < 8; ++ni) {
        int gc = ni * 16 + l15;
        float g = ln_g[l * DDIM + gc], bb = ln_b[l * DDIM + gc];
        #pragma unroll
        for (int r = 0; r < 4; ++r) {
            int gr = r0 + 4 * q + r;
            float mean = s[r] * (1.f / DDIM);
            float var = sq[r] * (1.f / DDIM) - mean * mean;
            float val = (vv[r][ni] - mean) * rsqrtf(var + 1e-5f) * g + bb;
            node_f[(size_t)gr * DDIM + gc] = val;
            unsigned short vb = f2bf(val);
            node_bf[(size_t)gr * DDIM + gc] = vb;
            xs_bf[(size_t)(2 * gr + l) * DDIM + gc] = vb;
        }
    }
}

// ---------------- qkv = xs x in_w^T + in_b : [8192,128]x[128,384] ---------------------
extern "C" __global__ __launch_bounds__(256)
void k_qkv(const unsigned short* __restrict__ xs_bf, const unsigned short* __restrict__ inw,
           const float* __restrict__ in_b, float* __restrict__ qkv)
{
    int wave = threadIdx.x >> 6, wm = wave >> 1, wn = wave & 1;
    int r0 = blockIdx.x * 64 + wm * 32;
    int c0 = blockIdx.y * 64 + wn * 32;
    floatx4 acc[2][2] = {};
    gemm32x32(xs_bf, inw, DDIM, r0, c0, acc);
    int lane = threadIdx.x & 63, l15 = lane & 15, q = lane >> 4;
    for (int mi = 0; mi < 2; ++mi)
        for (int ni = 0; ni < 2; ++ni) {
            int gc = c0 + ni * 16 + l15;
            float ib = in_b[gc];
            #pragma unroll
            for (int r = 0; r < 4; ++r) {
                int gr = r0 + mi * 16 + 4 * q + r;
                qkv[(size_t)gr * 384 + gc] = acc[mi][ni][r] + ib;
            }
        }
}

// ---------------- attention over L=2 (heads of 32 dims) -------------------------------
extern "C" __global__ __launch_bounds__(128)
void k_attn(const float* __restrict__ qkv, unsigned short* __restrict__ o_bf)
{
    int b = blockIdx.x, t = threadIdx.x;
    const float* base0 = qkv + (size_t)(2 * b) * 384;
    const float* base1 = base0 + 384;
    float q0 = base0[t], kk0 = base0[128 + t], v0 = base0[256 + t];
    float q1 = base1[t], kk1 = base1[128 + t], v1 = base1[256 + t];
    float s00 = q0 * kk0, s01 = q0 * kk1, s10 = q1 * kk0, s11 = q1 * kk1;
    #pragma unroll
    for (int off = 16; off >= 1; off >>= 1) {
        s00 += __shfl_xor(s00, off, 64);
        s01 += __shfl_xor(s01, off, 64);
        s10 += __shfl_xor(s10, off, 64);
        s11 += __shfl_xor(s11, off, 64);
    }
    const float sc = 0.17677669529663687f;   // 1/sqrt(32)
    s00 *= sc; s01 *= sc; s10 *= sc; s11 *= sc;
    float m0 = fmaxf(s00, s01), e00 = expf(s00 - m0), e01 = expf(s01 - m0);
    float i0 = 1.f / (e00 + e01);
    float m1 = fmaxf(s10, s11), e10 = expf(s10 - m1), e11 = expf(s11 - m1);
    float i1 = 1.f / (e10 + e11);
    o_bf[(size_t)(2 * b) * 128 + t]     = f2bf((e00 * v0 + e01 * v1) * i0);
    o_bf[(size_t)(2 * b + 1) * 128 + t] = f2bf((e10 * v0 + e11 * v1) * i1);
}

// ---------------- out-proj + mean over L + final LN -----------------------------------
extern "C" __global__ __launch_bounds__(256)
void k_out(const unsigned short* __restrict__ o_bf, const unsigned short* __restrict__ outw,
           const float* __restrict__ out_b, const float* __restrict__ fg,
           const float* __restrict__ fb, float* __restrict__ outp)
{
    int wave = threadIdx.x >> 6;
    int r0 = (blockIdx.x * 4 + wave) * 16;
    int lane = threadIdx.x & 63, l15 = lane & 15, q = lane >> 4;
    floatx4 acc[8] = {};
    const unsigned short* ap = o_bf + (size_t)(r0 + l15) * DDIM + q * 8;
    #pragma unroll
    for (int k = 0; k < DDIM; k += 32) {
        short8 A0 = *(const short8*)(ap + k);
        #pragma unroll
        for (int ni = 0; ni < 8; ++ni) {
            short8 B = *(const short8*)(outw + (size_t)(ni * 16 + l15) * DDIM + q * 8 + k);
            acc[ni] = __builtin_amdgcn_mfma_f32_16x16x32_bf16(A0, B, acc[ni], 0, 0, 0);
        }
    }
    float av[2][8];
    float s[2] = {0, 0}, sq[2] = {0, 0};
    #pragma unroll
    for (int ni = 0; ni < 8; ++ni) {
        int gc = ni * 16 + l15;
        float ob = out_b[gc];
        #pragma unroll
        for (int rr = 0; rr < 2; ++rr) {
            float v = 0.5f * (acc[ni][2 * rr] + acc[ni][2 * rr + 1]) + ob;
            av[rr][ni] = v; s[rr] += v; sq[rr] += v * v;
        }
    }
    #pragma unroll
    for (int rr = 0; rr < 2; ++rr)
        #pragma unroll
        for (int off = 8; off >= 1; off >>= 1) {
            s[rr] += __shfl_xor(s[rr], off, 64);
            sq[rr] += __shfl_xor(sq[rr], off, 64);
        }
    #pragma unroll
    for (int ni = 0; ni < 8; ++ni) {
        int gc = ni * 16 + l15;
        float g = fg[gc], bb = fb[gc];
        #pragma unroll
        for (int rr = 0; rr < 2; ++rr) {
            int bg = (r0 >> 1) + 2 * q + rr;
            float mean = s[rr] * (1.f / DDIM);
            float var = sq[rr] * (1.f / DDIM) - mean * mean;
            outp[(size_t)bg * DDIM + gc] = (av[rr][ni] - mean) * rsqrtf(var + 1e-5f) * g + bb;
        }
    }
}

extern "C" void kernel_launch(void* const* d_in, const int* in_sizes, int n_in,
                              void* d_out, int out_size, void* d_ws, size_t ws_size,
                              hipStream_t stream) {
    const int*   drug_idx = (const int*)d_in[0];
    const int*   adj_ent  = (const int*)d_in[1];
    const int*   adj_rel  = (const int*)d_in[2];
    const float* ew       = (const float*)d_in[3];
    const float* emb      = (const float*)d_in[4];
    const float* W_rgcn   = (const float*)d_in[5];
    const float* res_w    = (const float*)d_in[6];
    const float* res_b    = (const float*)d_in[7];
    const float* proj_w   = (const float*)d_in[8];
    const float* proj_b   = (const float*)d_in[9];
    const float* ln_g     = (const float*)d_in[10];
    const float* ln_b     = (const float*)d_in[11];
    const float* in_w     = (const float*)d_in[12];
    const float* in_b     = (const float*)d_in[13];
    const float* out_w    = (const float*)d_in[14];
    const float* out_b    = (const float*)d_in[15];
    const float* fg       = (const float*)d_in[16];
    const float* fb       = (const float*)d_in[17];
    float* outp = (float*)d_out;

    char* ws = (char*)d_ws;
    size_t off = 0;
    auto alloc = [&](size_t bytes) { size_t o = off; off = (off + bytes + 255) & ~(size_t)255; return o; };
    unsigned short* pre_bf  = (unsigned short*)(ws + alloc((size_t)BBATCH * 2048 * 2));
    float*          node_f  = (float*)         (ws + alloc((size_t)BBATCH * 128 * 4));
    unsigned short* node_bf = (unsigned short*)(ws + alloc((size_t)BBATCH * 128 * 2));
    unsigned short* xs_bf   = (unsigned short*)(ws + alloc((size_t)2 * BBATCH * 128 * 2));
    unsigned short* h_bf    = (unsigned short*)(ws + alloc((size_t)BBATCH * 128 * 2));
    float*          msgs    = (float*)         (ws + alloc((size_t)BBATCH * 256 * 4));
    float*          qkv     = (float*)         (ws + alloc((size_t)2 * BBATCH * 384 * 4));
    unsigned short* o_bf    = (unsigned short*)(ws + alloc((size_t)2 * BBATCH * 128 * 2));
    unsigned short* Wcat    = (unsigned short*)(ws + alloc((size_t)256 * 2048 * 2));
    unsigned short* resw    = (unsigned short*)(ws + alloc((size_t)2 * 128 * 128 * 2));
    unsigned short* projw   = (unsigned short*)(ws + alloc((size_t)2 * 128 * 128 * 2));
    unsigned short* inw     = (unsigned short*)(ws + alloc((size_t)384 * 128 * 2));
    unsigned short* outw    = (unsigned short*)(ws + alloc((size_t)128 * 128 * 2));

    hipLaunchKernelGGL(k_wconv, dim3(2560), dim3(256), 0, stream,
                       W_rgcn, res_w, proj_w, in_w, out_w, Wcat, resw, projw, inw, outw);
    hipLaunchKernelGGL(k_gather, dim3(BBATCH), dim3(128), 0, stream,
                       drug_idx, adj_ent, adj_rel, ew, emb, pre_bf, node_f, node_bf);
    hipLaunchKernelGGL(k_msgs, dim3(64, 4), dim3(256), 0, stream, pre_bf, Wcat, msgs);
    for (int l = 0; l < 2; ++l) {
        hipLaunchKernelGGL(k_res, dim3(64, 2), dim3(256), 0, stream,
                           node_bf, resw, res_b, node_f, msgs, h_bf, l);
        hipLaunchKernelGGL(k_proj, dim3(64), dim3(256), 0, stream,
                           h_bf, projw, proj_b, ln_g, ln_b, node_f, node_bf, xs_bf, l);
    }
    hipLaunchKernelGGL(k_qkv, dim3(128, 6), dim3(256), 0, stream, xs_bf, inw, in_b, qkv);
    hipLaunchKernelGGL(k_attn, dim3(BBATCH), dim3(128), 0, stream, qkv, o_bf);
    hipLaunchKernelGGL(k_out, dim3(128), dim3(256), 0, stream, o_bf, outw, out_b, fg, fb, outp);
}